// Round 2
// baseline (167.437 us; speedup 1.0000x reference)
//
#include <hip/hip_runtime.h>

typedef unsigned short ushort_t;
using short8 = __attribute__((ext_vector_type(8))) short;
using half8  = __attribute__((ext_vector_type(8))) _Float16;
using f32x4  = __attribute__((ext_vector_type(4))) float;

#define AS1 __attribute__((address_space(1)))
#define AS3 __attribute__((address_space(3)))

// Sizes (fixed by the problem)
#define B_   8
#define S_   2048
#define D_   1024
#define NIN  (8UL * 2048UL * 1024UL)    // input elements
#define NSC  (8UL * 2048UL * 2048UL)    // score elements
#define PARTS 32                        // 16 col-tiles x 2 wave-cols

__device__ __forceinline__ ushort_t f2bf(float f) {
    unsigned u = __float_as_uint(f);
    u += 0x7FFFu + ((u >> 16) & 1u);    // RNE (inputs are finite normals)
    return (ushort_t)(u >> 16);
}

// ================= PATH A (workspace-backed, fused) =================

// kernel A1: read X once -> exact f32 copy (out slot 0) + bf16 operand (ws)
__global__ __launch_bounds__(256) void cvtcopy_kernel(const float* __restrict__ in,
                                                      float* __restrict__ outcopy,
                                                      ushort_t* __restrict__ xbf) {
    size_t i = ((size_t)blockIdx.x * 256 + threadIdx.x) * 8;
    const float4* p = (const float4*)(in + i);
    float4 a = p[0], c = p[1];
    float4* q = (float4*)(outcopy + i);
    q[0] = a; q[1] = c;
    short8 r;
    r[0] = (short)f2bf(a.x); r[1] = (short)f2bf(a.y);
    r[2] = (short)f2bf(a.z); r[3] = (short)f2bf(a.w);
    r[4] = (short)f2bf(c.x); r[5] = (short)f2bf(c.y);
    r[6] = (short)f2bf(c.z); r[7] = (short)f2bf(c.w);
    *(short8*)(xbf + i) = r;
}

// kernel A2: per-batch logits = X X^T / 2048; epilogue: e = exp(logit) -> f16,
// plus per-(row, coltile, wavecol) partial row sums (each slot written once).
__global__ __launch_bounds__(256) void gemm_exp(const ushort_t* __restrict__ X,
                                                _Float16* __restrict__ E,
                                                float* __restrict__ part) {
    __shared__ __align__(16) ushort_t sA[128 * 64];
    __shared__ __align__(16) ushort_t sB[128 * 64];

    const int b = blockIdx.z;
    const ushort_t* Xb = X + (size_t)b * (S_ * D_);
    _Float16* Eb = E + (size_t)b * (S_ * S_);

    const int tr = blockIdx.y * 128;
    const int tc = blockIdx.x * 128;
    const int tid  = threadIdx.x;
    const int lane = tid & 63;
    const int wid  = tid >> 6;
    const int wr = (wid >> 1) * 64;
    const int wc = (wid & 1) * 64;

    f32x4 acc[4][4] = {};

    const int srow = tid >> 3;
    const int scol = (tid & 7) * 8;
    const int rsel = lane & 15;
    const int ksel = (lane >> 4) * 8;

    for (int kt = 0; kt < D_ / 64; ++kt) {
        const int k0 = kt * 64;
        if (kt) __syncthreads();
#pragma unroll
        for (int c = 0; c < 4; ++c) {
            const ushort_t* gA = Xb + (size_t)(tr + c * 32 + srow) * D_ + k0 + scol;
            const ushort_t* gB = Xb + (size_t)(tc + c * 32 + srow) * D_ + k0 + scol;
            __builtin_amdgcn_global_load_lds((const AS1 void*)gA,
                                             (AS3 void*)(sA + c * 2048 + tid * 8), 16, 0, 0);
            __builtin_amdgcn_global_load_lds((const AS1 void*)gB,
                                             (AS3 void*)(sB + c * 2048 + tid * 8), 16, 0, 0);
        }
        __syncthreads();

#pragma unroll
        for (int kk = 0; kk < 2; ++kk) {
            const int kb = kk * 32 + ksel;
            short8 af[4], bf[4];
#pragma unroll
            for (int m = 0; m < 4; ++m)
                af[m] = *(const short8*)&sA[(wr + m * 16 + rsel) * 64 + kb];
#pragma unroll
            for (int n = 0; n < 4; ++n)
                bf[n] = *(const short8*)&sB[(wc + n * 16 + rsel) * 64 + kb];
#pragma unroll
            for (int m = 0; m < 4; ++m) {
#pragma unroll
                for (int n = 0; n < 4; ++n) {
                    acc[m][n] = __builtin_amdgcn_mfma_f32_16x16x32_bf16(
                        af[m], bf[n], acc[m][n], 0, 0, 0);
                }
            }
        }
    }

    // epilogue: e = exp(logit/2048) -> f16; accumulate per-row partial sums
    const float scale = 1.0f / 2048.0f;
    const int r0 = (lane >> 4) * 4;
    const int c0 = lane & 15;
    float rsum[4][4];
#pragma unroll
    for (int m = 0; m < 4; ++m)
#pragma unroll
        for (int r = 0; r < 4; ++r) rsum[m][r] = 0.0f;

#pragma unroll
    for (int m = 0; m < 4; ++m) {
#pragma unroll
        for (int n = 0; n < 4; ++n) {
            _Float16* dst = Eb + (size_t)(tr + wr + m * 16 + r0) * S_ + (tc + wc + n * 16 + c0);
#pragma unroll
            for (int r = 0; r < 4; ++r) {
                float e = __expf(acc[m][n][r] * scale);
                dst[(size_t)r * S_] = (_Float16)e;
                rsum[m][r] += e;
            }
        }
    }

    // reduce row sums across the 16 lanes sharing each row (lane&15)
#pragma unroll
    for (int m = 0; m < 4; ++m) {
#pragma unroll
        for (int r = 0; r < 4; ++r) {
            float s = rsum[m][r];
            s += __shfl_xor(s, 1, 64);
            s += __shfl_xor(s, 2, 64);
            s += __shfl_xor(s, 4, 64);
            s += __shfl_xor(s, 8, 64);
            if ((lane & 15) == 0) {
                size_t grow = (size_t)b * S_ + tr + wr + m * 16 + (lane >> 4) * 4 + r;
                part[grow * PARTS + blockIdx.x * 2 + (wid & 1)] = s;
            }
        }
    }
}

// kernel A3: scores[row][t] = E[row][t] / sum(part[row][:])
__global__ __launch_bounds__(256) void normalize_rows(const _Float16* __restrict__ E,
                                                      const float* __restrict__ part,
                                                      float* __restrict__ S) {
    const int row  = blockIdx.x * 4 + (threadIdx.x >> 6);
    const int lane = threadIdx.x & 63;

    float p = (lane < PARTS) ? part[(size_t)row * PARTS + lane] : 0.0f;
#pragma unroll
    for (int o = 32; o > 0; o >>= 1) p += __shfl_xor(p, o, 64);
    const float inv = 1.0f / p;

    const _Float16* e = E + (size_t)row * S_;
    float* s = S + (size_t)row * S_;
#pragma unroll
    for (int c = 0; c < 4; ++c) {
        const int idx = (c * 64 + lane) * 8;
        half8 v = *(const half8*)(e + idx);
        float4 f0, f1;
        f0.x = (float)v[0] * inv; f0.y = (float)v[1] * inv;
        f0.z = (float)v[2] * inv; f0.w = (float)v[3] * inv;
        f1.x = (float)v[4] * inv; f1.y = (float)v[5] * inv;
        f1.z = (float)v[6] * inv; f1.w = (float)v[7] * inv;
        *(float4*)(s + idx)     = f0;
        *(float4*)(s + idx + 4) = f1;
    }
}

// ================= PATH B (fallback, round-1 proven) =================

__global__ __launch_bounds__(256) void cvt_kernel(const float* __restrict__ in,
                                                  ushort_t* __restrict__ ob) {
    size_t i = ((size_t)blockIdx.x * 256 + threadIdx.x) * 8;
    const float4* p = (const float4*)(in + i);
    float4 a = p[0], c = p[1];
    short8 r;
    r[0] = (short)f2bf(a.x); r[1] = (short)f2bf(a.y);
    r[2] = (short)f2bf(a.z); r[3] = (short)f2bf(a.w);
    r[4] = (short)f2bf(c.x); r[5] = (short)f2bf(c.y);
    r[6] = (short)f2bf(c.z); r[7] = (short)f2bf(c.w);
    *(short8*)(ob + i) = r;
}

__global__ __launch_bounds__(256) void gemm_xxt(const ushort_t* __restrict__ X,
                                                float* __restrict__ S) {
    __shared__ __align__(16) ushort_t sA[128 * 64];
    __shared__ __align__(16) ushort_t sB[128 * 64];

    const int b = blockIdx.z;
    const ushort_t* Xb = X + (size_t)b * (S_ * D_);
    float* Sb = S + (size_t)b * (S_ * S_);

    const int tr = blockIdx.y * 128;
    const int tc = blockIdx.x * 128;
    const int tid  = threadIdx.x;
    const int lane = tid & 63;
    const int wid  = tid >> 6;
    const int wr = (wid >> 1) * 64;
    const int wc = (wid & 1) * 64;

    f32x4 acc[4][4] = {};

    const int srow = tid >> 3;
    const int scol = (tid & 7) * 8;
    const int rsel = lane & 15;
    const int ksel = (lane >> 4) * 8;

    for (int kt = 0; kt < D_ / 64; ++kt) {
        const int k0 = kt * 64;
        if (kt) __syncthreads();
#pragma unroll
        for (int c = 0; c < 4; ++c) {
            const ushort_t* gA = Xb + (size_t)(tr + c * 32 + srow) * D_ + k0 + scol;
            const ushort_t* gB = Xb + (size_t)(tc + c * 32 + srow) * D_ + k0 + scol;
            __builtin_amdgcn_global_load_lds((const AS1 void*)gA,
                                             (AS3 void*)(sA + c * 2048 + tid * 8), 16, 0, 0);
            __builtin_amdgcn_global_load_lds((const AS1 void*)gB,
                                             (AS3 void*)(sB + c * 2048 + tid * 8), 16, 0, 0);
        }
        __syncthreads();

#pragma unroll
        for (int kk = 0; kk < 2; ++kk) {
            const int kb = kk * 32 + ksel;
            short8 af[4], bf[4];
#pragma unroll
            for (int m = 0; m < 4; ++m)
                af[m] = *(const short8*)&sA[(wr + m * 16 + rsel) * 64 + kb];
#pragma unroll
            for (int n = 0; n < 4; ++n)
                bf[n] = *(const short8*)&sB[(wc + n * 16 + rsel) * 64 + kb];
#pragma unroll
            for (int m = 0; m < 4; ++m) {
#pragma unroll
                for (int n = 0; n < 4; ++n) {
                    acc[m][n] = __builtin_amdgcn_mfma_f32_16x16x32_bf16(
                        af[m], bf[n], acc[m][n], 0, 0, 0);
                }
            }
        }
    }

    const float scale = 1.0f / 2048.0f;
    const int r0 = (lane >> 4) * 4;
    const int c0 = lane & 15;
#pragma unroll
    for (int m = 0; m < 4; ++m) {
#pragma unroll
        for (int n = 0; n < 4; ++n) {
            float* dst = Sb + (size_t)(tr + wr + m * 16 + r0) * S_ + (tc + wc + n * 16 + c0);
#pragma unroll
            for (int r = 0; r < 4; ++r)
                dst[(size_t)r * S_] = acc[m][n][r] * scale;
        }
    }
}

__global__ __launch_bounds__(256) void softmax_rows(float* __restrict__ S) {
    const int row  = blockIdx.x * 4 + (threadIdx.x >> 6);
    const int lane = threadIdx.x & 63;
    float4* p = (float4*)(S + (size_t)row * S_);

    float4 v[8];
    float mx = -3.0e38f;
#pragma unroll
    for (int i = 0; i < 8; ++i) {
        v[i] = p[i * 64 + lane];
        mx = fmaxf(mx, fmaxf(fmaxf(v[i].x, v[i].y), fmaxf(v[i].z, v[i].w)));
    }
#pragma unroll
    for (int o = 32; o > 0; o >>= 1) mx = fmaxf(mx, __shfl_xor(mx, o, 64));

    float sum = 0.0f;
#pragma unroll
    for (int i = 0; i < 8; ++i) {
        v[i].x = __expf(v[i].x - mx);
        v[i].y = __expf(v[i].y - mx);
        v[i].z = __expf(v[i].z - mx);
        v[i].w = __expf(v[i].w - mx);
        sum += (v[i].x + v[i].y) + (v[i].z + v[i].w);
    }
#pragma unroll
    for (int o = 32; o > 0; o >>= 1) sum += __shfl_xor(sum, o, 64);

    const float rs = 1.0f / sum;
#pragma unroll
    for (int i = 0; i < 8; ++i) {
        v[i].x *= rs; v[i].y *= rs; v[i].z *= rs; v[i].w *= rs;
        p[i * 64 + lane] = v[i];
    }
}

__global__ __launch_bounds__(256) void copy_kernel(const float4* __restrict__ in,
                                                   float4* __restrict__ out) {
    size_t i = (size_t)blockIdx.x * 256 + threadIdx.x;
    out[i] = in[i];
}

// ================= launcher =================

extern "C" void kernel_launch(void* const* d_in, const int* in_sizes, int n_in,
                              void* d_out, int out_size, void* d_ws, size_t ws_size,
                              hipStream_t stream) {
    const float* X = (const float*)d_in[0];
    float* out     = (float*)d_out;
    float* scores  = out + NIN;

    const size_t XBF_BYTES = NIN * 2;           //  67,108,864  bf16 X
    const size_t EXP_BYTES = NSC * 2;           //  67,108,864  f16 exp
    const size_t PART_BYTES = (size_t)B_ * S_ * PARTS * 4;  // 2 MB
    const size_t NEED = XBF_BYTES + EXP_BYTES + PART_BYTES;

    if (ws_size >= NEED) {
        // Path A: fused, workspace-backed
        ushort_t* xbf  = (ushort_t*)d_ws;
        _Float16* E    = (_Float16*)((char*)d_ws + XBF_BYTES);
        float*    part = (float*)((char*)d_ws + XBF_BYTES + EXP_BYTES);

        cvtcopy_kernel<<<NIN / (256 * 8), 256, 0, stream>>>(X, out, xbf);

        dim3 g(S_ / 128, S_ / 128, B_);
        gemm_exp<<<g, 256, 0, stream>>>(xbf, E, part);

        normalize_rows<<<(B_ * S_) / 4, 256, 0, stream>>>(E, part, scores);
    } else {
        // Path B: proven round-1 pipeline (no workspace dependency)
        ushort_t* xbf = (ushort_t*)d_out;   // park bf16 X in output slot 0

        cvt_kernel<<<NIN / (256 * 8), 256, 0, stream>>>(X, xbf);

        dim3 g(S_ / 128, S_ / 128, B_);
        gemm_xxt<<<g, 256, 0, stream>>>(xbf, scores);

        softmax_rows<<<(B_ * S_) / 4, 256, 0, stream>>>(scores);

        copy_kernel<<<NIN / (256 * 4), 256, 0, stream>>>((const float4*)X, (float4*)out);
    }
}

// Round 3
// 152.300 us; speedup vs baseline: 1.0994x; 1.0994x over previous
//
#include <hip/hip_runtime.h>

typedef unsigned short ushort_t;
using short8 = __attribute__((ext_vector_type(8))) short;
using half4  = __attribute__((ext_vector_type(4))) _Float16;
using half8  = __attribute__((ext_vector_type(8))) _Float16;
using f32x4  = __attribute__((ext_vector_type(4))) float;

#define AS1 __attribute__((address_space(1)))
#define AS3 __attribute__((address_space(3)))

// Problem sizes (fixed)
#define B_   8
#define S_   2048
#define D_   1024
#define NIN  (8UL * 2048UL * 1024UL)    // input elements (16,777,216)
#define PARTS 32                        // 16 col-tiles x 2 wave-slots per row
#define SROWB 8192UL                    // bytes per f32 score row
#define BATCHB (2048UL * SROWB)         // bytes per batch in score region (16.78 MB)

__device__ __forceinline__ ushort_t f2bf(float f) {
    unsigned u = __float_as_uint(f);
    u += 0x7FFFu + ((u >> 16) & 1u);    // RNE (finite normals only)
    return (ushort_t)(u >> 16);
}

// ---------- cvt (Path B): f32 -> contiguous bf16 in out slot 0 ----------
__global__ __launch_bounds__(256) void cvt_kernel(const float* __restrict__ in,
                                                  ushort_t* __restrict__ ob) {
    size_t i = ((size_t)blockIdx.x * 256 + threadIdx.x) * 8;
    const float4* p = (const float4*)(in + i);
    float4 a = p[0], c = p[1];
    short8 r;
    r[0] = (short)f2bf(a.x); r[1] = (short)f2bf(a.y);
    r[2] = (short)f2bf(a.z); r[3] = (short)f2bf(a.w);
    r[4] = (short)f2bf(c.x); r[5] = (short)f2bf(c.y);
    r[6] = (short)f2bf(c.z); r[7] = (short)f2bf(c.w);
    *(short8*)(ob + i) = r;
}

// ---------- cvtcopy (Path A): one X read -> exact f32 copy + packed bf16 ----------
// bf16 X of batch b parks in the FIRST halves of score rows [b*2048, b*2048+1024):
// X row rho (2048B) at  sc + b*BATCHB + (rho>>1)*8192 + (rho&1)*2048
__global__ __launch_bounds__(256) void cvtcopy_packed(const float* __restrict__ in,
                                                      float* __restrict__ outcopy,
                                                      char* sc) {
    size_t g = ((size_t)blockIdx.x * 256 + threadIdx.x) * 8;
    const float4* p = (const float4*)(in + g);
    float4 a = p[0], c = p[1];
    float4* q = (float4*)(outcopy + g);
    q[0] = a; q[1] = c;
    short8 r;
    r[0] = (short)f2bf(a.x); r[1] = (short)f2bf(a.y);
    r[2] = (short)f2bf(a.z); r[3] = (short)f2bf(a.w);
    r[4] = (short)f2bf(c.x); r[5] = (short)f2bf(c.y);
    r[6] = (short)f2bf(c.z); r[7] = (short)f2bf(c.w);
    size_t xrow = g >> 10;                 // global X row
    size_t col  = g & 1023;
    size_t b    = xrow >> 11;
    size_t rho  = xrow & 2047;
    char* dst = sc + b * BATCHB + (rho >> 1) * SROWB + (rho & 1) * 2048 + col * 2;
    *(short8*)dst = r;
}

// ---------- symmetric GEMM + exp epilogue ----------
// Computes upper-triangular 128x128 tiles (ti<=tj) of S = X X^T / 2048 per batch.
// Writes e=exp(s) as f16 into per-row parking (row*8192+4096) for BOTH (i,j) and
// its mirror (j,i); emits per-(row, tile, wave) partial row sums (each slot once).
template<bool PACKED>
__global__ __launch_bounds__(256) void gemm_sym(const char* xbase, char* sc,
                                                float* part) {
    __shared__ __align__(16) ushort_t sA[128 * 64];
    __shared__ __align__(16) ushort_t sB[128 * 64];

    const int b = blockIdx.z;
    // decode linear tile id -> (ti, tj), ti <= tj
    int rem = blockIdx.x, ti = 0;
    while (rem >= 16 - ti) { rem -= 16 - ti; ++ti; }
    const int tj = ti + rem;
    const int tr = ti * 128, tc = tj * 128;

    const char* Xb = xbase + (PACKED ? (size_t)b * BATCHB : (size_t)b * (2048UL * 2048UL));
    char* Eb = sc + (size_t)b * BATCHB;

    const int tid  = threadIdx.x;
    const int lane = tid & 63;
    const int wid  = tid >> 6;
    const int wr = (wid >> 1) * 64;
    const int wc = (wid & 1) * 64;

    f32x4 acc[4][4] = {};

    const int srow = tid >> 3;
    const int scol = (tid & 7) * 8;
    const int rsel = lane & 15;
    const int ksel = (lane >> 4) * 8;

    auto rowoff = [](int r) -> size_t {
        return PACKED ? ((size_t)(r >> 1) * SROWB + (size_t)(r & 1) * 2048)
                      : (size_t)r * 2048;
    };

    for (int kt = 0; kt < D_ / 64; ++kt) {
        const int k0 = kt * 64;
        if (kt) __syncthreads();
#pragma unroll
        for (int c = 0; c < 4; ++c) {
            const char* gA = Xb + rowoff(tr + c * 32 + srow) + (size_t)(k0 + scol) * 2;
            const char* gB = Xb + rowoff(tc + c * 32 + srow) + (size_t)(k0 + scol) * 2;
            __builtin_amdgcn_global_load_lds((const AS1 void*)gA,
                                             (AS3 void*)(sA + c * 2048 + tid * 8), 16, 0, 0);
            __builtin_amdgcn_global_load_lds((const AS1 void*)gB,
                                             (AS3 void*)(sB + c * 2048 + tid * 8), 16, 0, 0);
        }
        __syncthreads();

#pragma unroll
        for (int kk = 0; kk < 2; ++kk) {
            const int kb = kk * 32 + ksel;
            short8 af[4], bf[4];
#pragma unroll
            for (int m = 0; m < 4; ++m)
                af[m] = *(const short8*)&sA[(wr + m * 16 + rsel) * 64 + kb];
#pragma unroll
            for (int n = 0; n < 4; ++n)
                bf[n] = *(const short8*)&sB[(wc + n * 16 + rsel) * 64 + kb];
#pragma unroll
            for (int m = 0; m < 4; ++m) {
#pragma unroll
                for (int n = 0; n < 4; ++n) {
                    acc[m][n] = __builtin_amdgcn_mfma_f32_16x16x32_bf16(
                        af[m], bf[n], acc[m][n], 0, 0, 0);
                }
            }
        }
    }

    const float scale = 1.0f / 2048.0f;
    const int r0 = (lane >> 4) * 4;
    const int c0 = lane & 15;

    // exp in place (logits bounded ~[-0.25, 0.75]; no max-shift needed)
#pragma unroll
    for (int m = 0; m < 4; ++m)
#pragma unroll
        for (int n = 0; n < 4; ++n)
#pragma unroll
            for (int rr = 0; rr < 4; ++rr)
                acc[m][n][rr] = __expf(acc[m][n][rr] * scale);

    // direct tile writes: E[tr+..][tc+..] (f16 at row second-half)
#pragma unroll
    for (int m = 0; m < 4; ++m) {
#pragma unroll
        for (int n = 0; n < 4; ++n) {
            char* dbase = Eb + (size_t)(tr + wr + m * 16 + r0) * SROWB + 4096
                             + (size_t)(tc + wc + n * 16 + c0) * 2;
#pragma unroll
            for (int rr = 0; rr < 4; ++rr)
                *(_Float16*)(dbase + (size_t)rr * SROWB) = (_Float16)acc[m][n][rr];
        }
    }

    // row sums for direct rows -> slot tj*2 + wave-col
#pragma unroll
    for (int m = 0; m < 4; ++m) {
#pragma unroll
        for (int rr = 0; rr < 4; ++rr) {
            float s = (acc[m][0][rr] + acc[m][1][rr]) + (acc[m][2][rr] + acc[m][3][rr]);
            s += __shfl_xor(s, 1, 64);
            s += __shfl_xor(s, 2, 64);
            s += __shfl_xor(s, 4, 64);
            s += __shfl_xor(s, 8, 64);
            if ((lane & 15) == 0) {
                size_t grow = (size_t)b * S_ + tr + wr + m * 16 + r0 + rr;
                part[grow * PARTS + tj * 2 + (wid & 1)] = s;
            }
        }
    }

    if (ti != tj) {
        // mirror writes: E[tc+c][tr+r] — 4 consecutive rows of a column pack
        // into one aligned 8B f16x4 store
#pragma unroll
        for (int m = 0; m < 4; ++m) {
#pragma unroll
            for (int n = 0; n < 4; ++n) {
                half4 h;
#pragma unroll
                for (int rr = 0; rr < 4; ++rr) h[rr] = (_Float16)acc[m][n][rr];
                char* mb = Eb + (size_t)(tc + wc + n * 16 + c0) * SROWB + 4096
                              + (size_t)(tr + wr + m * 16 + r0) * 2;
                *(half4*)mb = h;
            }
        }
        // column sums = mirror-row sums -> slot ti*2 + wave-row
#pragma unroll
        for (int n = 0; n < 4; ++n) {
            float s = 0.0f;
#pragma unroll
            for (int m = 0; m < 4; ++m)
#pragma unroll
                for (int rr = 0; rr < 4; ++rr) s += acc[m][n][rr];
            s += __shfl_xor(s, 16, 64);
            s += __shfl_xor(s, 32, 64);
            if (lane < 16) {
                size_t gcol = (size_t)b * S_ + tc + wc + n * 16 + lane;
                part[gcol * PARTS + ti * 2 + (wid >> 1)] = s;
            }
        }
    }
}

// ---------- normalize: f16 exps (row second half) -> f32 scores (full row), in place ----------
// NOTE: sc is deliberately NOT __restrict__ — e and s alias the same row, and the
// may-alias assumption keeps all loads ordered before the expanding stores.
__global__ __launch_bounds__(256) void normalize_rows(char* sc, const float* part) {
    const int row  = blockIdx.x * 4 + (threadIdx.x >> 6);
    const int lane = threadIdx.x & 63;
    char* rowc = sc + (size_t)row * SROWB;
    const _Float16* e = (const _Float16*)(rowc + 4096);
    float* s = (float*)rowc;

    float p = (lane < PARTS) ? part[(size_t)row * PARTS + lane] : 0.0f;
#pragma unroll
    for (int o = 32; o > 0; o >>= 1) p += __shfl_xor(p, o, 64);
    const float inv = 1.0f / p;

    half8 v[4];
#pragma unroll
    for (int c = 0; c < 4; ++c)
        v[c] = *(const half8*)(e + c * 512 + lane * 8);

#pragma unroll
    for (int c = 0; c < 4; ++c) {
        float4 f0, f1;
        f0.x = (float)v[c][0] * inv; f0.y = (float)v[c][1] * inv;
        f0.z = (float)v[c][2] * inv; f0.w = (float)v[c][3] * inv;
        f1.x = (float)v[c][4] * inv; f1.y = (float)v[c][5] * inv;
        f1.z = (float)v[c][6] * inv; f1.w = (float)v[c][7] * inv;
        *(float4*)(s + c * 512 + lane * 8)     = f0;
        *(float4*)(s + c * 512 + lane * 8 + 4) = f1;
    }
}

// ---------- exact f32 input copy (Path B tail) ----------
__global__ __launch_bounds__(256) void copy_kernel(const float4* __restrict__ in,
                                                   float4* __restrict__ out) {
    size_t i = (size_t)blockIdx.x * 256 + threadIdx.x;
    out[i] = in[i];
}

// ---------- launcher ----------
extern "C" void kernel_launch(void* const* d_in, const int* in_sizes, int n_in,
                              void* d_out, int out_size, void* d_ws, size_t ws_size,
                              hipStream_t stream) {
    const float* X = (const float*)d_in[0];
    float* out = (float*)d_out;
    char*  sc  = (char*)d_out + NIN * 4;           // scores region base
    const size_t PART_BYTES = (size_t)B_ * S_ * PARTS * 4;   // 2 MB

    if (ws_size >= PART_BYTES) {
        // Path A: partials in workspace; bf16 X parked inside score region;
        // exact f32 copy fused into the single X read.
        float* part = (float*)d_ws;
        cvtcopy_packed<<<NIN / (256 * 8), 256, 0, stream>>>(X, out, sc);
        gemm_sym<true><<<dim3(136, 1, B_), 256, 0, stream>>>(sc, sc, part);
        normalize_rows<<<(B_ * S_) / 4, 256, 0, stream>>>(sc, part);
    } else {
        // Path B: no workspace needed. bf16 X + partials live in out slot 0,
        // which the exact copy overwrites last.
        ushort_t* xbf = (ushort_t*)d_out;
        float* part = (float*)((char*)d_out + NIN * 2);
        cvt_kernel<<<NIN / (256 * 8), 256, 0, stream>>>(X, xbf);
        gemm_sym<false><<<dim3(136, 1, B_), 256, 0, stream>>>((const char*)d_out, sc, part);
        normalize_rows<<<(B_ * S_) / 4, 256, 0, stream>>>(sc, part);
        copy_kernel<<<NIN / (256 * 4), 256, 0, stream>>>((const float4*)X, (float4*)out);
    }
}

// Round 4
// 149.658 us; speedup vs baseline: 1.1188x; 1.0176x over previous
//
#include <hip/hip_runtime.h>

typedef unsigned short ushort_t;
using short8 = __attribute__((ext_vector_type(8))) short;
using half4  = __attribute__((ext_vector_type(4))) _Float16;
using half8  = __attribute__((ext_vector_type(8))) _Float16;
using f32x4  = __attribute__((ext_vector_type(4))) float;

#define AS1 __attribute__((address_space(1)))
#define AS3 __attribute__((address_space(3)))

// Problem sizes (fixed)
#define B_   8
#define S_   2048
#define D_   1024
#define NIN  (8UL * 2048UL * 1024UL)    // input elements (16,777,216)
#define PARTS 32                        // 16 col-tiles x 2 wave-slots per row
#define SROWB 8192UL                    // bytes per f32 score row
#define BATCHB (2048UL * SROWB)         // bytes per batch in score region

// Per-score-row layout during the pipeline (all inside the scores region of d_out):
//   [0,128)     : 32 f32 partial row sums   (gemm -> normalize)
//   [2048,4096) : bf16 X row                (cvtcopy -> gemm)
//   [4096,8192) : f16 E row = exp(logits)   (gemm -> normalize)
// normalize overwrites the whole row with final f32 scores.

__device__ __forceinline__ ushort_t f2bf(float f) {
    unsigned u = __float_as_uint(f);
    u += 0x7FFFu + ((u >> 16) & 1u);    // RNE (finite normals only)
    return (ushort_t)(u >> 16);
}

// ---------- kernel 1: one X read -> exact f32 copy (out slot 0) + parked bf16 ----------
__global__ __launch_bounds__(256) void cvtcopy_packed(const float* __restrict__ in,
                                                      float* __restrict__ outcopy,
                                                      char* sc) {
    size_t g = ((size_t)blockIdx.x * 256 + threadIdx.x) * 8;
    const float4* p = (const float4*)(in + g);
    float4 a = p[0], c = p[1];
    float4* q = (float4*)(outcopy + g);
    q[0] = a; q[1] = c;
    short8 r;
    r[0] = (short)f2bf(a.x); r[1] = (short)f2bf(a.y);
    r[2] = (short)f2bf(a.z); r[3] = (short)f2bf(a.w);
    r[4] = (short)f2bf(c.x); r[5] = (short)f2bf(c.y);
    r[6] = (short)f2bf(c.z); r[7] = (short)f2bf(c.w);
    size_t xrow = g >> 10;                 // global X row (b*2048 + rho)
    size_t col  = g & 1023;
    char* dst = sc + xrow * SROWB + 2048 + col * 2;   // BATCHB == 2048*SROWB
    *(short8*)dst = r;
}

// ---------- kernel 2: symmetric GEMM + exp epilogue ----------
// Upper-triangular 128x128 tiles (ti<=tj) of S = X X^T / 2048 per batch.
// Writes e=exp(s) f16 for BOTH (i,j) and mirror (j,i); partial row sums to
// each row's own [0,128) slot range (each slot written exactly once).
__global__ __launch_bounds__(256) void gemm_sym(char* sc) {
    __shared__ __align__(16) ushort_t sA[128 * 64];
    __shared__ __align__(16) ushort_t sB[128 * 64];

    const int b = blockIdx.z;
    int rem = blockIdx.x, ti = 0;
    while (rem >= 16 - ti) { rem -= 16 - ti; ++ti; }
    const int tj = ti + rem;
    const int tr = ti * 128, tc = tj * 128;

    char* Sb = sc + (size_t)b * BATCHB;

    const int tid  = threadIdx.x;
    const int lane = tid & 63;
    const int wid  = tid >> 6;
    const int wr = (wid >> 1) * 64;
    const int wc = (wid & 1) * 64;

    f32x4 acc[4][4] = {};

    const int srow = tid >> 3;
    const int scol = (tid & 7) * 8;
    const int rsel = lane & 15;
    const int ksel = (lane >> 4) * 8;

    for (int kt = 0; kt < D_ / 64; ++kt) {
        const int k0 = kt * 64;
        if (kt) __syncthreads();
#pragma unroll
        for (int c = 0; c < 4; ++c) {
            const char* gA = Sb + (size_t)(tr + c * 32 + srow) * SROWB + 2048
                                + (size_t)(k0 + scol) * 2;
            const char* gB = Sb + (size_t)(tc + c * 32 + srow) * SROWB + 2048
                                + (size_t)(k0 + scol) * 2;
            __builtin_amdgcn_global_load_lds((const AS1 void*)gA,
                                             (AS3 void*)(sA + c * 2048 + tid * 8), 16, 0, 0);
            __builtin_amdgcn_global_load_lds((const AS1 void*)gB,
                                             (AS3 void*)(sB + c * 2048 + tid * 8), 16, 0, 0);
        }
        __syncthreads();

#pragma unroll
        for (int kk = 0; kk < 2; ++kk) {
            const int kb = kk * 32 + ksel;
            short8 af[4], bf[4];
#pragma unroll
            for (int m = 0; m < 4; ++m)
                af[m] = *(const short8*)&sA[(wr + m * 16 + rsel) * 64 + kb];
#pragma unroll
            for (int n = 0; n < 4; ++n)
                bf[n] = *(const short8*)&sB[(wc + n * 16 + rsel) * 64 + kb];
#pragma unroll
            for (int m = 0; m < 4; ++m) {
#pragma unroll
                for (int n = 0; n < 4; ++n) {
                    acc[m][n] = __builtin_amdgcn_mfma_f32_16x16x32_bf16(
                        af[m], bf[n], acc[m][n], 0, 0, 0);
                }
            }
        }
    }

    const float scale = 1.0f / 2048.0f;
    const int r0 = (lane >> 4) * 4;
    const int c0 = lane & 15;

    // exp in place (logits bounded ~[-0.3, 0.8] for N(0,1) data; no max-shift needed;
    // even a 10x outlier stays far inside f32/f16 range)
#pragma unroll
    for (int m = 0; m < 4; ++m)
#pragma unroll
        for (int n = 0; n < 4; ++n)
#pragma unroll
            for (int rr = 0; rr < 4; ++rr)
                acc[m][n][rr] = __expf(acc[m][n][rr] * scale);

    // direct tile writes: E[tr+..][tc+..]
#pragma unroll
    for (int m = 0; m < 4; ++m) {
#pragma unroll
        for (int n = 0; n < 4; ++n) {
            char* dbase = Sb + (size_t)(tr + wr + m * 16 + r0) * SROWB + 4096
                             + (size_t)(tc + wc + n * 16 + c0) * 2;
#pragma unroll
            for (int rr = 0; rr < 4; ++rr)
                *(_Float16*)(dbase + (size_t)rr * SROWB) = (_Float16)acc[m][n][rr];
        }
    }

    // direct row sums -> own-row slot tj*2 + (wid&1)
#pragma unroll
    for (int m = 0; m < 4; ++m) {
#pragma unroll
        for (int rr = 0; rr < 4; ++rr) {
            float s = (acc[m][0][rr] + acc[m][1][rr]) + (acc[m][2][rr] + acc[m][3][rr]);
            s += __shfl_xor(s, 1, 64);
            s += __shfl_xor(s, 2, 64);
            s += __shfl_xor(s, 4, 64);
            s += __shfl_xor(s, 8, 64);
            if ((lane & 15) == 0) {
                char* prow = Sb + (size_t)(tr + wr + m * 16 + r0 + rr) * SROWB;
                ((float*)prow)[tj * 2 + (wid & 1)] = s;
            }
        }
    }

    if (ti != tj) {
        // mirror writes: E[tc+c][tr+r] — 4 consecutive rows of one column pack
        // into a single aligned 8B f16x4 store
#pragma unroll
        for (int m = 0; m < 4; ++m) {
#pragma unroll
            for (int n = 0; n < 4; ++n) {
                half4 h;
#pragma unroll
                for (int rr = 0; rr < 4; ++rr) h[rr] = (_Float16)acc[m][n][rr];
                char* mb = Sb + (size_t)(tc + wc + n * 16 + c0) * SROWB + 4096
                              + (size_t)(tr + wr + m * 16 + r0) * 2;
                *(half4*)mb = h;
            }
        }
        // column sums = mirror-row sums -> own-row slot ti*2 + (wid>>1)
#pragma unroll
        for (int n = 0; n < 4; ++n) {
            float s = 0.0f;
#pragma unroll
            for (int m = 0; m < 4; ++m)
#pragma unroll
                for (int rr = 0; rr < 4; ++rr) s += acc[m][n][rr];
            s += __shfl_xor(s, 16, 64);
            s += __shfl_xor(s, 32, 64);
            if (lane < 16) {
                char* prow = Sb + (size_t)(tc + wc + n * 16 + lane) * SROWB;
                ((float*)prow)[ti * 2 + (wid >> 1)] = s;
            }
        }
    }
}

// ---------- kernel 3: normalize each row in place ----------
// Reads own-row partials [0,128) + f16 E [4096,8192); writes f32 scores [0,8192).
// sc deliberately NOT __restrict__ (loads must order before the expanding stores).
__global__ __launch_bounds__(256) void normalize_rows(char* sc) {
    const int row  = blockIdx.x * 4 + (threadIdx.x >> 6);
    const int lane = threadIdx.x & 63;
    char* rowc = sc + (size_t)row * SROWB;
    const _Float16* e = (const _Float16*)(rowc + 4096);
    float* s = (float*)rowc;

    float p = (lane < PARTS) ? ((const float*)rowc)[lane] : 0.0f;
#pragma unroll
    for (int o = 32; o > 0; o >>= 1) p += __shfl_xor(p, o, 64);
    const float inv = 1.0f / p;

    half8 v[4];
#pragma unroll
    for (int c = 0; c < 4; ++c)
        v[c] = *(const half8*)(e + c * 512 + lane * 8);

#pragma unroll
    for (int c = 0; c < 4; ++c) {
        float4 f0, f1;
        f0.x = (float)v[c][0] * inv; f0.y = (float)v[c][1] * inv;
        f0.z = (float)v[c][2] * inv; f0.w = (float)v[c][3] * inv;
        f1.x = (float)v[c][4] * inv; f1.y = (float)v[c][5] * inv;
        f1.z = (float)v[c][6] * inv; f1.w = (float)v[c][7] * inv;
        *(float4*)(s + c * 512 + lane * 8)     = f0;
        *(float4*)(s + c * 512 + lane * 8 + 4) = f1;
    }
}

// ---------- launcher (single path, no workspace needed) ----------
extern "C" void kernel_launch(void* const* d_in, const int* in_sizes, int n_in,
                              void* d_out, int out_size, void* d_ws, size_t ws_size,
                              hipStream_t stream) {
    const float* X = (const float*)d_in[0];
    float* out = (float*)d_out;
    char*  sc  = (char*)d_out + NIN * 4;     // scores region base

    cvtcopy_packed<<<NIN / (256 * 8), 256, 0, stream>>>(X, out, sc);
    gemm_sym<<<dim3(136, 1, B_), 256, 0, stream>>>(sc);
    normalize_rows<<<(B_ * S_) / 4, 256, 0, stream>>>(sc);
}

// Round 5
// 123.631 us; speedup vs baseline: 1.3543x; 1.2105x over previous
//
#include <hip/hip_runtime.h>

typedef unsigned short ushort_t;
using short8 = __attribute__((ext_vector_type(8))) short;
using half4  = __attribute__((ext_vector_type(4))) _Float16;
using half8  = __attribute__((ext_vector_type(8))) _Float16;
using f32x4  = __attribute__((ext_vector_type(4))) float;

#define AS1 __attribute__((address_space(1)))
#define AS3 __attribute__((address_space(3)))

// Problem sizes (fixed)
#define B_   8
#define S_   2048
#define D_   1024
#define NIN  (8UL * 2048UL * 1024UL)
#define PARTS 32
#define SROWB 8192UL
#define BATCHB (2048UL * SROWB)

// Per-score-row layout during the pipeline:
//   [0,128)     : 32 f32 partial row sums   (gemm -> normalize)
//   [2048,4096) : bf16 X row                (cvtcopy -> gemm)
//   [4096,8192) : f16 E row = exp(logits)   (gemm -> normalize)
// normalize overwrites the whole row with final f32 scores.

__device__ __forceinline__ ushort_t f2bf(float f) {
    unsigned u = __float_as_uint(f);
    u += 0x7FFFu + ((u >> 16) & 1u);
    return (ushort_t)(u >> 16);
}

// ---------- kernel 1: one X read -> exact f32 copy + parked bf16 ----------
__global__ __launch_bounds__(256) void cvtcopy_packed(const float* __restrict__ in,
                                                      float* __restrict__ outcopy,
                                                      char* sc) {
    size_t g = ((size_t)blockIdx.x * 256 + threadIdx.x) * 8;
    const float4* p = (const float4*)(in + g);
    float4 a = p[0], c = p[1];
    float4* q = (float4*)(outcopy + g);
    q[0] = a; q[1] = c;
    short8 r;
    r[0] = (short)f2bf(a.x); r[1] = (short)f2bf(a.y);
    r[2] = (short)f2bf(a.z); r[3] = (short)f2bf(a.w);
    r[4] = (short)f2bf(c.x); r[5] = (short)f2bf(c.y);
    r[6] = (short)f2bf(c.z); r[7] = (short)f2bf(c.w);
    size_t xrow = g >> 10;
    size_t col  = g & 1023;
    char* dst = sc + xrow * SROWB + 2048 + col * 2;
    *(short8*)dst = r;
}

// ---------- kernel 2: symmetric GEMM, ring-2 counted-vmcnt pipeline ----------
// Upper-triangular 128x128 tiles of S = X X^T / 2048 per batch; exp epilogue,
// direct + mirror f16 writes, per-row partial sums (each slot written once).
__global__ __launch_bounds__(256, 2) void gemm_sym2(char* sc) {
    // ring of 2 K-slices (BK=64) per matrix: 4 x 16KB = 64KB LDS
    __shared__ __align__(16) ushort_t sA[2][128 * 64];
    __shared__ __align__(16) ushort_t sB[2][128 * 64];

    // bijective XCD swizzle: 1088 = 8 * 136, each XCD gets one batch's 136 tiles
    const int lin = blockIdx.x;
    const int wg  = (lin & 7) * 136 + (lin >> 3);
    const int b   = wg / 136;
    int rem = wg % 136, ti = 0;
    while (rem >= 16 - ti) { rem -= 16 - ti; ++ti; }
    const int tj = ti + rem;
    const int tr = ti * 128, tc = tj * 128;

    char* Sb = sc + (size_t)b * BATCHB;

    const int tid  = threadIdx.x;
    const int lane = tid & 63;
    const int wid  = tid >> 6;
    const int wr = (wid >> 1) * 64;
    const int wc = (wid & 1) * 64;

    f32x4 acc[4][4] = {};

    // staging geometry: per slice, 4 gload_lds x (A,B); instr j covers rows j*32..+31,
    // thread t -> row j*32 + (t>>3), 16B chunk cd = t&7, source chunk pre-swizzled.
    const int srow_s = tid >> 3;
    const int cd     = tid & 7;
    // fragment read geometry
    const int rsel = lane & 15;
    const int g4   = lane >> 4;
    const int sw   = lane & 7;          // (row & 7) for all frag rows

    auto stage = [&](int s, int slot) {
#pragma unroll
        for (int j = 0; j < 4; ++j) {
            const int row = j * 32 + srow_s;
            const int csw = (cd ^ (row & 7)) << 4;        // pre-swizzled source chunk
            const size_t rbA = (size_t)(tr + row) * SROWB + 2048 + (size_t)s * 128;
            const size_t rbB = (size_t)(tc + row) * SROWB + 2048 + (size_t)s * 128;
            __builtin_amdgcn_global_load_lds((const AS1 void*)(Sb + rbA + csw),
                (AS3 void*)((char*)&sA[slot][0] + j * 4096 + tid * 16), 16, 0, 0);
            __builtin_amdgcn_global_load_lds((const AS1 void*)(Sb + rbB + csw),
                (AS3 void*)((char*)&sB[slot][0] + j * 4096 + tid * 16), 16, 0, 0);
        }
    };

    // prologue: slices 0,1 -> slots 0,1; wait own slice-0 (8 newest = slice 1)
    stage(0, 0);
    stage(1, 1);
    asm volatile("s_waitcnt vmcnt(8)" ::: "memory");
    __builtin_amdgcn_s_barrier();

#pragma unroll
    for (int s = 0; s < 16; ++s) {
        const int slot = s & 1;

        // ds_read all fragments of slice s (swizzled chunks)
        short8 af[2][4], bfr[2][4];
#pragma unroll
        for (int kk = 0; kk < 2; ++kk) {
            const int cb = kk * 4 + g4;
            const int csw = (cb ^ sw) << 4;
#pragma unroll
            for (int m = 0; m < 4; ++m) {
                const int row = wr + m * 16 + rsel;
                af[kk][m] = *(const short8*)((const char*)&sA[slot][0] + row * 128 + csw);
            }
#pragma unroll
            for (int n = 0; n < 4; ++n) {
                const int row = wc + n * 16 + rsel;
                bfr[kk][n] = *(const short8*)((const char*)&sB[slot][0] + row * 128 + csw);
            }
        }
        asm volatile("s_waitcnt lgkmcnt(0)" ::: "memory");
        __builtin_amdgcn_s_barrier();        // B1: all waves' reads of slice s done

        if (s + 2 < 16) {
            stage(s + 2, slot);              // overwrite just-read slot
            asm volatile("s_waitcnt vmcnt(8)" ::: "memory");  // own slice s+1 landed
        } else if (s == 14) {
            asm volatile("s_waitcnt vmcnt(0)" ::: "memory");  // slice 15 landed
        }
        __builtin_amdgcn_s_barrier();        // B2: everyone's slice s+1 landed

        __builtin_amdgcn_s_setprio(1);
#pragma unroll
        for (int kk = 0; kk < 2; ++kk)
#pragma unroll
            for (int m = 0; m < 4; ++m)
#pragma unroll
                for (int n = 0; n < 4; ++n)
                    acc[m][n] = __builtin_amdgcn_mfma_f32_16x16x32_bf16(
                        af[kk][m], bfr[kk][n], acc[m][n], 0, 0, 0);
        __builtin_amdgcn_s_setprio(0);
    }

    // ---------------- epilogue (unchanged from R4) ----------------
    const float scale = 1.0f / 2048.0f;
    const int r0 = (lane >> 4) * 4;
    const int c0 = lane & 15;

#pragma unroll
    for (int m = 0; m < 4; ++m)
#pragma unroll
        for (int n = 0; n < 4; ++n)
#pragma unroll
            for (int rr = 0; rr < 4; ++rr)
                acc[m][n][rr] = __expf(acc[m][n][rr] * scale);

#pragma unroll
    for (int m = 0; m < 4; ++m) {
#pragma unroll
        for (int n = 0; n < 4; ++n) {
            char* dbase = Sb + (size_t)(tr + wr + m * 16 + r0) * SROWB + 4096
                             + (size_t)(tc + wc + n * 16 + c0) * 2;
#pragma unroll
            for (int rr = 0; rr < 4; ++rr)
                *(_Float16*)(dbase + (size_t)rr * SROWB) = (_Float16)acc[m][n][rr];
        }
    }

#pragma unroll
    for (int m = 0; m < 4; ++m) {
#pragma unroll
        for (int rr = 0; rr < 4; ++rr) {
            float s = (acc[m][0][rr] + acc[m][1][rr]) + (acc[m][2][rr] + acc[m][3][rr]);
            s += __shfl_xor(s, 1, 64);
            s += __shfl_xor(s, 2, 64);
            s += __shfl_xor(s, 4, 64);
            s += __shfl_xor(s, 8, 64);
            if ((lane & 15) == 0) {
                char* prow = Sb + (size_t)(tr + wr + m * 16 + r0 + rr) * SROWB;
                ((float*)prow)[tj * 2 + (wid & 1)] = s;
            }
        }
    }

    if (ti != tj) {
#pragma unroll
        for (int m = 0; m < 4; ++m) {
#pragma unroll
            for (int n = 0; n < 4; ++n) {
                half4 h;
#pragma unroll
                for (int rr = 0; rr < 4; ++rr) h[rr] = (_Float16)acc[m][n][rr];
                char* mb = Sb + (size_t)(tc + wc + n * 16 + c0) * SROWB + 4096
                              + (size_t)(tr + wr + m * 16 + r0) * 2;
                *(half4*)mb = h;
            }
        }
#pragma unroll
        for (int n = 0; n < 4; ++n) {
            float s = 0.0f;
#pragma unroll
            for (int m = 0; m < 4; ++m)
#pragma unroll
                for (int rr = 0; rr < 4; ++rr) s += acc[m][n][rr];
            s += __shfl_xor(s, 16, 64);
            s += __shfl_xor(s, 32, 64);
            if (lane < 16) {
                char* prow = Sb + (size_t)(tc + wc + n * 16 + lane) * SROWB;
                ((float*)prow)[ti * 2 + (wid >> 1)] = s;
            }
        }
    }
}

// ---------- kernel 3: normalize each row in place ----------
__global__ __launch_bounds__(256) void normalize_rows(char* sc) {
    const int row  = blockIdx.x * 4 + (threadIdx.x >> 6);
    const int lane = threadIdx.x & 63;
    char* rowc = sc + (size_t)row * SROWB;
    const _Float16* e = (const _Float16*)(rowc + 4096);
    float* s = (float*)rowc;

    float p = (lane < PARTS) ? ((const float*)rowc)[lane] : 0.0f;
#pragma unroll
    for (int o = 32; o > 0; o >>= 1) p += __shfl_xor(p, o, 64);
    const float inv = 1.0f / p;

    half8 v[4];
#pragma unroll
    for (int c = 0; c < 4; ++c)
        v[c] = *(const half8*)(e + c * 512 + lane * 8);

#pragma unroll
    for (int c = 0; c < 4; ++c) {
        float4 f0, f1;
        f0.x = (float)v[c][0] * inv; f0.y = (float)v[c][1] * inv;
        f0.z = (float)v[c][2] * inv; f0.w = (float)v[c][3] * inv;
        f1.x = (float)v[c][4] * inv; f1.y = (float)v[c][5] * inv;
        f1.z = (float)v[c][6] * inv; f1.w = (float)v[c][7] * inv;
        *(float4*)(s + c * 512 + lane * 8)     = f0;
        *(float4*)(s + c * 512 + lane * 8 + 4) = f1;
    }
}

// ---------- launcher ----------
extern "C" void kernel_launch(void* const* d_in, const int* in_sizes, int n_in,
                              void* d_out, int out_size, void* d_ws, size_t ws_size,
                              hipStream_t stream) {
    const float* X = (const float*)d_in[0];
    float* out = (float*)d_out;
    char*  sc  = (char*)d_out + NIN * 4;

    cvtcopy_packed<<<NIN / (256 * 8), 256, 0, stream>>>(X, out, sc);
    gemm_sym2<<<1088, 256, 0, stream>>>(sc);
    normalize_rows<<<(B_ * S_) / 4, 256, 0, stream>>>(sc);
}

// Round 6
// 118.835 us; speedup vs baseline: 1.4090x; 1.0404x over previous
//
#include <hip/hip_runtime.h>

typedef unsigned short ushort_t;
using short8 = __attribute__((ext_vector_type(8))) short;
using half4  = __attribute__((ext_vector_type(4))) _Float16;
using half8  = __attribute__((ext_vector_type(8))) _Float16;
using f32x4  = __attribute__((ext_vector_type(4))) float;

#define AS1 __attribute__((address_space(1)))
#define AS3 __attribute__((address_space(3)))

// Problem sizes (fixed)
#define B_   8
#define S_   2048
#define D_   1024
#define NIN  (8UL * 2048UL * 1024UL)
#define PARTS 32
#define SROWB 8192UL
#define BATCHB (2048UL * SROWB)

// Per-score-row layout during the pipeline:
//   [0,128)     : 32 f32 partial row sums   (gemm -> normalize)
//   [2048,4096) : bf16 X row                (cvt -> gemm)
//   [4096,8192) : f16 E row = exp(logits)   (gemm -> normalize)
// normalize overwrites the whole row with final f32 scores.
// The exact f32 input copy is streamed through the gemm's idle VMEM slots.

__device__ __forceinline__ ushort_t f2bf(float f) {
    unsigned u = __float_as_uint(f);
    u += 0x7FFFu + ((u >> 16) & 1u);
    return (ushort_t)(u >> 16);
}

// ---------- kernel 1: f32 X -> parked bf16 (no copy half anymore) ----------
__global__ __launch_bounds__(256) void cvt_packed(const float* __restrict__ in,
                                                  char* sc) {
    size_t g = ((size_t)blockIdx.x * 256 + threadIdx.x) * 8;
    const float4* p = (const float4*)(in + g);
    float4 a = p[0], c = p[1];
    short8 r;
    r[0] = (short)f2bf(a.x); r[1] = (short)f2bf(a.y);
    r[2] = (short)f2bf(a.z); r[3] = (short)f2bf(a.w);
    r[4] = (short)f2bf(c.x); r[5] = (short)f2bf(c.y);
    r[6] = (short)f2bf(c.z); r[7] = (short)f2bf(c.w);
    size_t xrow = g >> 10;
    size_t col  = g & 1023;
    char* dst = sc + xrow * SROWB + 2048 + col * 2;
    *(short8*)dst = r;
}

// ---------- kernel 2: symmetric GEMM, ring-2 counted-vmcnt + embedded copy ----------
__global__ __launch_bounds__(256, 2) void gemm_sym3(char* sc,
                                                    const float4* xin,
                                                    float4* xout) {
    __shared__ __align__(16) ushort_t sA[2][128 * 64];
    __shared__ __align__(16) ushort_t sB[2][128 * 64];

    const int lin = blockIdx.x;
    // bijective XCD swizzle: 1088 = 8 * 136
    const int wg  = (lin & 7) * 136 + (lin >> 3);
    const int b   = wg / 136;
    int rem = wg % 136, ti = 0;
    while (rem >= 16 - ti) { rem -= 16 - ti; ++ti; }
    const int tj = ti + rem;
    const int tr = ti * 128, tc = tj * 128;

    char* Sb = sc + (size_t)b * BATCHB;

    const int tid  = threadIdx.x;
    const int lane = tid & 63;
    const int wid  = tid >> 6;
    const int wr = (wid >> 1) * 64;
    const int wc = (wid & 1) * 64;

    // embedded-copy geometry: blocks lin<1024 copy 2^22 float4 bijectively,
    // one load + one store per thread per phase (16 phases)
    const bool docopy = (lin < 1024);
    const size_t cbase = (size_t)lin * 256 + tid;   // < 262144 when docopy

    f32x4 acc[4][4] = {};
    float4 creg;

    const int srow_s = tid >> 3;
    const int cd     = tid & 7;
    const int rsel = lane & 15;
    const int g4   = lane >> 4;
    const int sw   = lane & 7;

    auto stage = [&](int s, int slot) {
#pragma unroll
        for (int j = 0; j < 4; ++j) {
            const int row = j * 32 + srow_s;
            const int csw = (cd ^ (row & 7)) << 4;
            const size_t rbA = (size_t)(tr + row) * SROWB + 2048 + (size_t)s * 128;
            const size_t rbB = (size_t)(tc + row) * SROWB + 2048 + (size_t)s * 128;
            __builtin_amdgcn_global_load_lds((const AS1 void*)(Sb + rbA + csw),
                (AS3 void*)((char*)&sA[slot][0] + j * 4096 + tid * 16), 16, 0, 0);
            __builtin_amdgcn_global_load_lds((const AS1 void*)(Sb + rbB + csw),
                (AS3 void*)((char*)&sB[slot][0] + j * 4096 + tid * 16), 16, 0, 0);
        }
    };

    // prologue
    stage(0, 0);
    stage(1, 1);
    asm volatile("s_waitcnt vmcnt(8)" ::: "memory");
    __builtin_amdgcn_s_barrier();

#pragma unroll
    for (int s = 0; s < 16; ++s) {
        const int slot = s & 1;

        short8 af[2][4], bfr[2][4];
#pragma unroll
        for (int kk = 0; kk < 2; ++kk) {
            const int cb = kk * 4 + g4;
            const int csw = (cb ^ sw) << 4;
#pragma unroll
            for (int m = 0; m < 4; ++m) {
                const int row = wr + m * 16 + rsel;
                af[kk][m] = *(const short8*)((const char*)&sA[slot][0] + row * 128 + csw);
            }
#pragma unroll
            for (int n = 0; n < 4; ++n) {
                const int row = wc + n * 16 + rsel;
                bfr[kk][n] = *(const short8*)((const char*)&sB[slot][0] + row * 128 + csw);
            }
        }
        asm volatile("s_waitcnt lgkmcnt(0)" ::: "memory");
        __builtin_amdgcn_s_barrier();        // B1: reads of slice s done everywhere

        if (s + 2 < 16) stage(s + 2, slot);  // overwrite just-read slot

        if (docopy) {
            if (s > 0) xout[cbase + (size_t)(s - 1) * 262144] = creg;  // store chunk s-1
            creg = xin[cbase + (size_t)s * 262144];                    // load chunk s
        }

        // counted waits: guarantee stage(s+1) landed; copies/stage(s+2) stay in flight.
        // W(s) = (prev-phase copy tail) + (this phase's issued ops before the wait).
        if (docopy) {
            if (s == 0)       asm volatile("s_waitcnt vmcnt(9)"  ::: "memory");
            else if (s == 1)  asm volatile("s_waitcnt vmcnt(11)" ::: "memory");
            else if (s < 14)  asm volatile("s_waitcnt vmcnt(12)" ::: "memory");
            else if (s == 14) asm volatile("s_waitcnt vmcnt(4)"  ::: "memory");
        } else {
            if (s + 2 < 16)   asm volatile("s_waitcnt vmcnt(8)"  ::: "memory");
            else if (s == 14) asm volatile("s_waitcnt vmcnt(0)"  ::: "memory");
        }
        __builtin_amdgcn_s_barrier();        // B2: everyone's slice s+1 resident

        __builtin_amdgcn_s_setprio(1);
#pragma unroll
        for (int kk = 0; kk < 2; ++kk)
#pragma unroll
            for (int m = 0; m < 4; ++m)
#pragma unroll
                for (int n = 0; n < 4; ++n)
                    acc[m][n] = __builtin_amdgcn_mfma_f32_16x16x32_bf16(
                        af[kk][m], bfr[kk][n], acc[m][n], 0, 0, 0);
        __builtin_amdgcn_s_setprio(0);
    }

    if (docopy) xout[cbase + 15UL * 262144] = creg;   // final copy chunk

    // ---------------- epilogue (unchanged) ----------------
    const float scale = 1.0f / 2048.0f;
    const int r0 = (lane >> 4) * 4;
    const int c0 = lane & 15;

#pragma unroll
    for (int m = 0; m < 4; ++m)
#pragma unroll
        for (int n = 0; n < 4; ++n)
#pragma unroll
            for (int rr = 0; rr < 4; ++rr)
                acc[m][n][rr] = __expf(acc[m][n][rr] * scale);

#pragma unroll
    for (int m = 0; m < 4; ++m) {
#pragma unroll
        for (int n = 0; n < 4; ++n) {
            char* dbase = Sb + (size_t)(tr + wr + m * 16 + r0) * SROWB + 4096
                             + (size_t)(tc + wc + n * 16 + c0) * 2;
#pragma unroll
            for (int rr = 0; rr < 4; ++rr)
                *(_Float16*)(dbase + (size_t)rr * SROWB) = (_Float16)acc[m][n][rr];
        }
    }

#pragma unroll
    for (int m = 0; m < 4; ++m) {
#pragma unroll
        for (int rr = 0; rr < 4; ++rr) {
            float s = (acc[m][0][rr] + acc[m][1][rr]) + (acc[m][2][rr] + acc[m][3][rr]);
            s += __shfl_xor(s, 1, 64);
            s += __shfl_xor(s, 2, 64);
            s += __shfl_xor(s, 4, 64);
            s += __shfl_xor(s, 8, 64);
            if ((lane & 15) == 0) {
                char* prow = Sb + (size_t)(tr + wr + m * 16 + r0 + rr) * SROWB;
                ((float*)prow)[tj * 2 + (wid & 1)] = s;
            }
        }
    }

    if (ti != tj) {
#pragma unroll
        for (int m = 0; m < 4; ++m) {
#pragma unroll
            for (int n = 0; n < 4; ++n) {
                half4 h;
#pragma unroll
                for (int rr = 0; rr < 4; ++rr) h[rr] = (_Float16)acc[m][n][rr];
                char* mb = Sb + (size_t)(tc + wc + n * 16 + c0) * SROWB + 4096
                              + (size_t)(tr + wr + m * 16 + r0) * 2;
                *(half4*)mb = h;
            }
        }
#pragma unroll
        for (int n = 0; n < 4; ++n) {
            float s = 0.0f;
#pragma unroll
            for (int m = 0; m < 4; ++m)
#pragma unroll
                for (int rr = 0; rr < 4; ++rr) s += acc[m][n][rr];
            s += __shfl_xor(s, 16, 64);
            s += __shfl_xor(s, 32, 64);
            if (lane < 16) {
                char* prow = Sb + (size_t)(tc + wc + n * 16 + lane) * SROWB;
                ((float*)prow)[ti * 2 + (wid >> 1)] = s;
            }
        }
    }
}

// ---------- kernel 3: normalize each row in place ----------
__global__ __launch_bounds__(256) void normalize_rows(char* sc) {
    const int row  = blockIdx.x * 4 + (threadIdx.x >> 6);
    const int lane = threadIdx.x & 63;
    char* rowc = sc + (size_t)row * SROWB;
    const _Float16* e = (const _Float16*)(rowc + 4096);
    float* s = (float*)rowc;

    float p = (lane < PARTS) ? ((const float*)rowc)[lane] : 0.0f;
#pragma unroll
    for (int o = 32; o > 0; o >>= 1) p += __shfl_xor(p, o, 64);
    const float inv = 1.0f / p;

    half8 v[4];
#pragma unroll
    for (int c = 0; c < 4; ++c)
        v[c] = *(const half8*)(e + c * 512 + lane * 8);

#pragma unroll
    for (int c = 0; c < 4; ++c) {
        float4 f0, f1;
        f0.x = (float)v[c][0] * inv; f0.y = (float)v[c][1] * inv;
        f0.z = (float)v[c][2] * inv; f0.w = (float)v[c][3] * inv;
        f1.x = (float)v[c][4] * inv; f1.y = (float)v[c][5] * inv;
        f1.z = (float)v[c][6] * inv; f1.w = (float)v[c][7] * inv;
        *(float4*)(s + c * 512 + lane * 8)     = f0;
        *(float4*)(s + c * 512 + lane * 8 + 4) = f1;
    }
}

// ---------- launcher ----------
extern "C" void kernel_launch(void* const* d_in, const int* in_sizes, int n_in,
                              void* d_out, int out_size, void* d_ws, size_t ws_size,
                              hipStream_t stream) {
    const float* X = (const float*)d_in[0];
    float* out = (float*)d_out;
    char*  sc  = (char*)d_out + NIN * 4;

    cvt_packed<<<NIN / (256 * 8), 256, 0, stream>>>(X, sc);
    gemm_sym3<<<1088, 256, 0, stream>>>(sc, (const float4*)X, (float4*)out);
    normalize_rows<<<(B_ * S_) / 4, 256, 0, stream>>>(sc);
}